// Round 2
// baseline (537.290 us; speedup 1.0000x reference)
//
#include <hip/hip_runtime.h>

#pragma clang fp contract(off)

#define TDIM 256
#define CDIM 64
#define LQW 17   // words per Q/K LDS row (16 data + 1 pad)
#define LVT 65   // words per transposed-V LDS row (64 data + 1 pad)
#define SENT (-1e30f)

static constexpr float BOA = (float)(0.96963238 / 0.35815147);  // python double then f32 cast
static constexpr float COA = (float)(1.0 / 0.35815147);
static constexpr float AF  = 0.35815147f;
static constexpr float X0F = -0.6931f;

__device__ __forceinline__ int qi8(float x, float s) {
  float r = rintf(x / s);              // IEEE div + round-half-even, matches jnp
  r = fminf(fmaxf(r, -128.f), 127.f);
  return (int)r;
}

__device__ __forceinline__ int pack4q(float4 f, float s) {
  unsigned a = (unsigned)(qi8(f.x, s)) & 255u;
  unsigned b = (unsigned)(qi8(f.y, s)) & 255u;
  unsigned c = (unsigned)(qi8(f.z, s)) & 255u;
  unsigned d = (unsigned)(qi8(f.w, s)) & 255u;
  return (int)(a | (b << 8) | (c << 16) | (d << 24));
}

__device__ __forceinline__ int sx8(int w, int sh) {   // sign-extend byte sh of word w
  return (int)(signed char)((unsigned)w >> sh);
}

__device__ __forceinline__ int dot4(int a, int b, int c) {
#if __has_builtin(__builtin_amdgcn_sdot4)
  return __builtin_amdgcn_sdot4(a, b, c, false);
#else
  c += sx8(a, 0) * sx8(b, 0);
  c += sx8(a, 8) * sx8(b, 8);
  c += sx8(a, 16) * sx8(b, 16);
  c += sx8(a, 24) * sx8(b, 24);
  return c;
#endif
}

__global__ __launch_bounds__(256) void absmax3_kernel(
    const float4* __restrict__ q, const float4* __restrict__ k,
    const float4* __restrict__ v, unsigned* __restrict__ ws, int n4) {
  int tid = blockIdx.x * 256 + threadIdx.x;
  int stride = gridDim.x * 256;
  float m0 = 0.f, m1 = 0.f, m2 = 0.f;
  for (int i = tid; i < n4; i += stride) {
    float4 a = q[i];
    m0 = fmaxf(m0, fmaxf(fmaxf(fabsf(a.x), fabsf(a.y)), fmaxf(fabsf(a.z), fabsf(a.w))));
    float4 b = k[i];
    m1 = fmaxf(m1, fmaxf(fmaxf(fabsf(b.x), fabsf(b.y)), fmaxf(fabsf(b.z), fabsf(b.w))));
    float4 c = v[i];
    m2 = fmaxf(m2, fmaxf(fmaxf(fabsf(c.x), fabsf(c.y)), fmaxf(fabsf(c.z), fabsf(c.w))));
  }
#pragma unroll
  for (int off = 32; off > 0; off >>= 1) {
    m0 = fmaxf(m0, __shfl_xor(m0, off, 64));
    m1 = fmaxf(m1, __shfl_xor(m1, off, 64));
    m2 = fmaxf(m2, __shfl_xor(m2, off, 64));
  }
  if ((threadIdx.x & 63) == 0) {   // non-negative floats: uint compare == float compare
    atomicMax(ws + 0, __float_as_uint(m0));
    atomicMax(ws + 1, __float_as_uint(m1));
    atomicMax(ws + 2, __float_as_uint(m2));
  }
}

__global__ __launch_bounds__(256, 2) void head_kernel(
    const float* __restrict__ qg, const float* __restrict__ kg,
    const float* __restrict__ vg, const float* __restrict__ ws,
    float* __restrict__ out, int out_size) {
  __shared__ int qw[TDIM][LQW];
  __shared__ int kw[TDIM][LQW];
  __shared__ int vtw[CDIM][LVT];       // transposed V, int8 bytes, row stride 260B
  __shared__ unsigned warr[4][TDIM];   // per-wave softmax weights (0..256), u32 only

  const int tid = threadIdx.x;
  const int b = blockIdx.x;
  const int lane = tid & 63;
  const int wave = tid >> 6;

  // uniform scale pipeline constants (replicate reference f32 op order exactly)
  const float qsf = ws[0] / 127.f;
  const float ksf = ws[1] / 127.f;
  const float vsf = ws[2] / 127.f;
  const float sf = ksf * qsf;                       // wei_sf = k_sf * q_sf
  const float x0i = floorf(X0F / sf);               // x0_int (negative)
  const float bint = floorf(BOA / sf);              // b_int
  const float cint = floorf(COA / (sf * sf));       // c_int
  const float esf = ((AF * sf) * sf) * 0x1p-30f;    // exp_sf = A*sf*sf / 2^30
  const float emax = (cint * 0x1p30f) * esf;        // global max of exp_int*exp_sf
  const float s16 = emax / 32767.f;                 // QuantAct(16) scale
  const float clampv = 30.f * x0i;                  // N_EXP * x0_int

  // ---- load + quantize into LDS ----
  const float4* q4 = (const float4*)(qg + (size_t)b * (TDIM * CDIM));
  const float4* k4 = (const float4*)(kg + (size_t)b * (TDIM * CDIM));
  const float4* v4 = (const float4*)(vg + (size_t)b * (TDIM * CDIM));
  signed char* vtb = (signed char*)vtw;
#pragma unroll
  for (int i = 0; i < 16; ++i) {
    int vidx = i * 256 + tid;        // float4 index 0..4095
    int row = vidx >> 4, cw = vidx & 15;
    float4 f = q4[vidx];
    qw[row][cw] = pack4q(f, qsf);
    f = k4[vidx];
    kw[row][cw] = pack4q(f, ksf);
    f = v4[vidx];
    int c0 = cw << 2;
    vtb[(c0 + 0) * (LVT * 4) + row] = (signed char)qi8(f.x, vsf);
    vtb[(c0 + 1) * (LVT * 4) + row] = (signed char)qi8(f.y, vsf);
    vtb[(c0 + 2) * (LVT * 4) + row] = (signed char)qi8(f.z, vsf);
    vtb[(c0 + 3) * (LVT * 4) + row] = (signed char)qi8(f.w, vsf);
  }
  __syncthreads();

  // ---- per-row processing: wave w handles rows t = w, w+4, ... ----
  for (int t = wave; t < TDIM; t += 4) {
    const int nch = (t >> 6) + 1;   // active 64-column chunks
    const int* qrow = qw[t];

    float xi[4];
#pragma unroll
    for (int ch = 0; ch < 4; ++ch) {
      int s = (ch << 6) + lane;
      float xv = SENT;
      if (ch < nch && s <= t) {
        const int* krow = kw[s];
        int dot = 0;
#pragma unroll
        for (int w = 0; w < 16; ++w) dot = dot4(qrow[w], krow[w], dot);
        xv = (float)dot * 0.125f;   // exact x_int (multiple of 1/8)
      }
      xi[ch] = xv;
    }

    // row max across wave
    float m = fmaxf(fmaxf(xi[0], xi[1]), fmaxf(xi[2], xi[3]));
#pragma unroll
    for (int off = 32; off > 0; off >>= 1) m = fmaxf(m, __shfl_xor(m, off, 64));

    // integer softmax pipeline (exact f32 replica of reference)
    float ei[4];
    float lsum = 0.f;
#pragma unroll
    for (int ch = 0; ch < 4; ++ch) {
      float e = 0.f;
      if (xi[ch] > -1e29f) {
        float x = xi[ch] - m;                      // exact (multiples of 1/8)
        x = fmaxf(x, clampv);                      // N_EXP clamp
        float qv = floorf(x / x0i);                // IEEE div
        float r = x - x0i * qv;                    // exact
        float poly = (r + bint) * r + cint;        // no FMA (contract off)
        float ef = floorf(poly * exp2f(30.f - qv));
        ef = fmaxf(ef, 0.f);
        float xf = ef * esf;
        float v16 = rintf(xf / s16);               // QuantAct(16) round
        v16 = fminf(v16, 32767.f);
        e = (v16 * s16) / s16;                     // exp/exp_sf round-trip
      }
      ei[ch] = e;
      lsum += e;
    }
#pragma unroll
    for (int off = 32; off > 0; off >>= 1) lsum += __shfl_xor(lsum, off, 64);

    float factor = floorf(4294967296.f / lsum);
#pragma unroll
    for (int ch = 0; ch < 4; ++ch) {
      float wqf = floorf((ei[ch] * factor) * 0x1p-24f);   // 0..256
      wqf = fminf(fmaxf(wqf, 0.f), 256.f);                // defensive clamp
      warr[wave][(ch << 6) + lane] = (unsigned)wqf;
    }
    asm volatile("" ::: "memory");   // pin LDS write -> read ordering (same wave)

    // ---- PV: lane = output channel c; exact integer dot over s ----
    const unsigned* wq = warr[wave];
    const int* vrow = vtw[lane];
    int acc = 0;
    const int nwords = nch << 4;    // 4 s-values per word
    for (int j = 0; j < nwords; ++j) {
      int vw_ = vrow[j];
      acc += sx8(vw_, 0)  * (int)wq[4 * j + 0];
      acc += sx8(vw_, 8)  * (int)wq[4 * j + 1];
      acc += sx8(vw_, 16) * (int)wq[4 * j + 2];
      acc += sx8(vw_, 24) * (int)wq[4 * j + 3];
    }
    // out = (acc * v_sf / 256) * (1/256)
    float o = ((float)acc * vsf) * 0x1p-16f;
    out[((b * TDIM + t) * CDIM) + lane] = o;
  }

  if (b == 0 && tid == 0) out[out_size - 1] = 0.00390625f;  // wei_sf scalar output
}

extern "C" void kernel_launch(void* const* d_in, const int* in_sizes, int n_in,
                              void* d_out, int out_size, void* d_ws, size_t ws_size,
                              hipStream_t stream) {
  const float* q = (const float*)d_in[0];
  const float* k = (const float*)d_in[1];
  const float* v = (const float*)d_in[2];
  float* out = (float*)d_out;
  unsigned* ws = (unsigned*)d_ws;
  int n = in_sizes[0];               // B*T*C = 8388608
  int nb = n / (TDIM * CDIM);        // 512 batches

  hipMemsetAsync(d_ws, 0, 16, stream);
  absmax3_kernel<<<2048, 256, 0, stream>>>((const float4*)q, (const float4*)k,
                                           (const float4*)v, ws, n / 4);
  head_kernel<<<nb, 256, 0, stream>>>(q, k, v, (const float*)d_ws, out, out_size);
}

// Round 3
// 258.232 us; speedup vs baseline: 2.0806x; 2.0806x over previous
//
#include <hip/hip_runtime.h>

#pragma clang fp contract(off)

#define TDIM 256
#define CDIM 64
#define LQW 17   // words per Q/K LDS row (16 data + 1 pad)
#define LVT 65   // words per transposed-V LDS row (64 data + 1 pad)
#define SENT (-1e30f)
#define NPART 512           // stage-1 blocks
#define WS_PART_OFF 16      // float offset of partials in d_ws

static constexpr float BOA = (float)(0.96963238 / 0.35815147);  // python double then f32 cast
static constexpr float COA = (float)(1.0 / 0.35815147);
static constexpr float AF  = 0.35815147f;
static constexpr float X0F = -0.6931f;

__device__ __forceinline__ int qi8(float x, float s) {
  float r = rintf(x / s);              // IEEE div + round-half-even, matches jnp
  r = fminf(fmaxf(r, -128.f), 127.f);
  return (int)r;
}

__device__ __forceinline__ int pack4q(float4 f, float s) {
  unsigned a = (unsigned)(qi8(f.x, s)) & 255u;
  unsigned b = (unsigned)(qi8(f.y, s)) & 255u;
  unsigned c = (unsigned)(qi8(f.z, s)) & 255u;
  unsigned d = (unsigned)(qi8(f.w, s)) & 255u;
  return (int)(a | (b << 8) | (c << 16) | (d << 24));
}

__device__ __forceinline__ int sx8(int w, int sh) {   // sign-extend byte sh of word w
  return (int)(signed char)((unsigned)w >> sh);
}

__device__ __forceinline__ int dot4(int a, int b, int c) {
#if __has_builtin(__builtin_amdgcn_sdot4)
  return __builtin_amdgcn_sdot4(a, b, c, false);
#else
  c += sx8(a, 0) * sx8(b, 0);
  c += sx8(a, 8) * sx8(b, 8);
  c += sx8(a, 16) * sx8(b, 16);
  c += sx8(a, 24) * sx8(b, 24);
  return c;
#endif
}

// ---- stage 1: per-block max partials (no atomics) ----
__global__ __launch_bounds__(256) void absmax_partial_kernel(
    const float4* __restrict__ q, const float4* __restrict__ k,
    const float4* __restrict__ v, float* __restrict__ ws, int n4) {
  __shared__ float red[3][4];
  int tid = blockIdx.x * 256 + threadIdx.x;
  int stride = gridDim.x * 256;
  float m0 = 0.f, m1 = 0.f, m2 = 0.f;
  for (int i = tid; i < n4; i += stride) {
    float4 a = q[i];
    m0 = fmaxf(m0, fmaxf(fmaxf(fabsf(a.x), fabsf(a.y)), fmaxf(fabsf(a.z), fabsf(a.w))));
    float4 b = k[i];
    m1 = fmaxf(m1, fmaxf(fmaxf(fabsf(b.x), fabsf(b.y)), fmaxf(fabsf(b.z), fabsf(b.w))));
    float4 c = v[i];
    m2 = fmaxf(m2, fmaxf(fmaxf(fabsf(c.x), fabsf(c.y)), fmaxf(fabsf(c.z), fabsf(c.w))));
  }
#pragma unroll
  for (int off = 32; off > 0; off >>= 1) {
    m0 = fmaxf(m0, __shfl_xor(m0, off, 64));
    m1 = fmaxf(m1, __shfl_xor(m1, off, 64));
    m2 = fmaxf(m2, __shfl_xor(m2, off, 64));
  }
  int wave = threadIdx.x >> 6;
  if ((threadIdx.x & 63) == 0) {
    red[0][wave] = m0; red[1][wave] = m1; red[2][wave] = m2;
  }
  __syncthreads();
  if (threadIdx.x == 0) {
    ws[WS_PART_OFF + 0 * NPART + blockIdx.x] = fmaxf(fmaxf(red[0][0], red[0][1]), fmaxf(red[0][2], red[0][3]));
    ws[WS_PART_OFF + 1 * NPART + blockIdx.x] = fmaxf(fmaxf(red[1][0], red[1][1]), fmaxf(red[1][2], red[1][3]));
    ws[WS_PART_OFF + 2 * NPART + blockIdx.x] = fmaxf(fmaxf(red[2][0], red[2][1]), fmaxf(red[2][2], red[2][3]));
  }
}

// ---- stage 2: single block reduces NPART partials per tensor ----
__global__ __launch_bounds__(256) void absmax_final_kernel(float* __restrict__ ws) {
  __shared__ float red[3][4];
  int tid = threadIdx.x;
  int wave = tid >> 6, lane = tid & 63;
  float m[3];
#pragma unroll
  for (int j = 0; j < 3; ++j) {
    float v = fmaxf(ws[WS_PART_OFF + j * NPART + tid],
                    ws[WS_PART_OFF + j * NPART + tid + 256]);
#pragma unroll
    for (int off = 32; off > 0; off >>= 1) v = fmaxf(v, __shfl_xor(v, off, 64));
    if (lane == 0) red[j][wave] = v;
    m[j] = v;
  }
  __syncthreads();
  if (tid == 0) {
#pragma unroll
    for (int j = 0; j < 3; ++j)
      ws[j] = fmaxf(fmaxf(red[j][0], red[j][1]), fmaxf(red[j][2], red[j][3]));
  }
  (void)m;
}

__global__ __launch_bounds__(256, 2) void head_kernel(
    const float* __restrict__ qg, const float* __restrict__ kg,
    const float* __restrict__ vg, const float* __restrict__ ws,
    float* __restrict__ out, int out_size) {
  __shared__ int qw[TDIM][LQW];
  __shared__ int kw[TDIM][LQW];
  __shared__ int vtw[CDIM][LVT];       // transposed V, int8 bytes, row stride 260B
  __shared__ unsigned warr[4][TDIM];   // per-wave softmax weights (0..256), u32 only

  const int tid = threadIdx.x;
  const int b = blockIdx.x;
  const int lane = tid & 63;
  const int wave = tid >> 6;

  // uniform scale pipeline constants (replicate reference f32 op order exactly)
  const float qsf = ws[0] / 127.f;
  const float ksf = ws[1] / 127.f;
  const float vsf = ws[2] / 127.f;
  const float sf = ksf * qsf;                       // wei_sf = k_sf * q_sf
  const float x0i = floorf(X0F / sf);               // x0_int (negative)
  const float bint = floorf(BOA / sf);              // b_int
  const float cint = floorf(COA / (sf * sf));       // c_int
  const float esf = ((AF * sf) * sf) * 0x1p-30f;    // exp_sf = A*sf*sf / 2^30
  const float emax = (cint * 0x1p30f) * esf;        // global max of exp_int*exp_sf
  const float s16 = emax / 32767.f;                 // QuantAct(16) scale
  const float clampv = 30.f * x0i;                  // N_EXP * x0_int

  // ---- load + quantize into LDS ----
  const float4* q4 = (const float4*)(qg + (size_t)b * (TDIM * CDIM));
  const float4* k4 = (const float4*)(kg + (size_t)b * (TDIM * CDIM));
  const float4* v4 = (const float4*)(vg + (size_t)b * (TDIM * CDIM));
  signed char* vtb = (signed char*)vtw;
#pragma unroll
  for (int i = 0; i < 16; ++i) {
    int vidx = i * 256 + tid;        // float4 index 0..4095
    int row = vidx >> 4, cw = vidx & 15;
    float4 f = q4[vidx];
    qw[row][cw] = pack4q(f, qsf);
    f = k4[vidx];
    kw[row][cw] = pack4q(f, ksf);
    f = v4[vidx];
    int c0 = cw << 2;
    vtb[(c0 + 0) * (LVT * 4) + row] = (signed char)qi8(f.x, vsf);
    vtb[(c0 + 1) * (LVT * 4) + row] = (signed char)qi8(f.y, vsf);
    vtb[(c0 + 2) * (LVT * 4) + row] = (signed char)qi8(f.z, vsf);
    vtb[(c0 + 3) * (LVT * 4) + row] = (signed char)qi8(f.w, vsf);
  }
  __syncthreads();

  // ---- per-row processing: wave w handles rows t = w, w+4, ... ----
  for (int t = wave; t < TDIM; t += 4) {
    const int nch = (t >> 6) + 1;   // active 64-column chunks
    const int* qrow = qw[t];

    float xi[4];
#pragma unroll
    for (int ch = 0; ch < 4; ++ch) {
      int s = (ch << 6) + lane;
      float xv = SENT;
      if (ch < nch && s <= t) {
        const int* krow = kw[s];
        int dot = 0;
#pragma unroll
        for (int w = 0; w < 16; ++w) dot = dot4(qrow[w], krow[w], dot);
        xv = (float)dot * 0.125f;   // exact x_int (multiple of 1/8)
      }
      xi[ch] = xv;
    }

    // row max across wave
    float m = fmaxf(fmaxf(xi[0], xi[1]), fmaxf(xi[2], xi[3]));
#pragma unroll
    for (int off = 32; off > 0; off >>= 1) m = fmaxf(m, __shfl_xor(m, off, 64));

    // integer softmax pipeline (exact f32 replica of reference)
    float ei[4];
    float lsum = 0.f;
#pragma unroll
    for (int ch = 0; ch < 4; ++ch) {
      float e = 0.f;
      if (xi[ch] > -1e29f) {
        float x = xi[ch] - m;                      // exact (multiples of 1/8)
        x = fmaxf(x, clampv);                      // N_EXP clamp
        float qv = floorf(x / x0i);                // IEEE div
        float r = x - x0i * qv;                    // exact
        float poly = (r + bint) * r + cint;        // no FMA (contract off)
        float ef = floorf(poly * exp2f(30.f - qv));
        ef = fmaxf(ef, 0.f);
        float xf = ef * esf;
        float v16 = rintf(xf / s16);               // QuantAct(16) round
        v16 = fminf(v16, 32767.f);
        e = (v16 * s16) / s16;                     // exp/exp_sf round-trip
      }
      ei[ch] = e;
      lsum += e;
    }
#pragma unroll
    for (int off = 32; off > 0; off >>= 1) lsum += __shfl_xor(lsum, off, 64);

    float factor = floorf(4294967296.f / lsum);
#pragma unroll
    for (int ch = 0; ch < 4; ++ch) {
      float wqf = floorf((ei[ch] * factor) * 0x1p-24f);   // 0..256
      wqf = fminf(fmaxf(wqf, 0.f), 256.f);                // defensive clamp
      warr[wave][(ch << 6) + lane] = (unsigned)wqf;
    }
    asm volatile("" ::: "memory");   // pin LDS write -> read ordering (same wave)

    // ---- PV: lane = output channel c; exact integer dot over s ----
    const unsigned* wq = warr[wave];
    const int* vrow = vtw[lane];
    int acc = 0;
    const int nwords = nch << 4;    // 4 s-values per word
    for (int j = 0; j < nwords; ++j) {
      int vw_ = vrow[j];
      acc += sx8(vw_, 0)  * (int)wq[4 * j + 0];
      acc += sx8(vw_, 8)  * (int)wq[4 * j + 1];
      acc += sx8(vw_, 16) * (int)wq[4 * j + 2];
      acc += sx8(vw_, 24) * (int)wq[4 * j + 3];
    }
    // out = (acc * v_sf / 256) * (1/256)
    float o = ((float)acc * vsf) * 0x1p-16f;
    out[((b * TDIM + t) * CDIM) + lane] = o;
  }

  if (b == 0 && tid == 0) out[out_size - 1] = 0.00390625f;  // wei_sf scalar output
}

extern "C" void kernel_launch(void* const* d_in, const int* in_sizes, int n_in,
                              void* d_out, int out_size, void* d_ws, size_t ws_size,
                              hipStream_t stream) {
  const float* q = (const float*)d_in[0];
  const float* k = (const float*)d_in[1];
  const float* v = (const float*)d_in[2];
  float* out = (float*)d_out;
  float* ws = (float*)d_ws;
  int n = in_sizes[0];               // B*T*C = 8388608
  int nb = n / (TDIM * CDIM);        // 512 batches

  absmax_partial_kernel<<<NPART, 256, 0, stream>>>((const float4*)q, (const float4*)k,
                                                   (const float4*)v, ws, n / 4);
  absmax_final_kernel<<<1, 256, 0, stream>>>(ws);
  head_kernel<<<nb, 256, 0, stream>>>(q, k, v, (const float*)d_ws, out, out_size);
}

// Round 4
// 144.381 us; speedup vs baseline: 3.7213x; 1.7886x over previous
//
#include <hip/hip_runtime.h>

#pragma clang fp contract(off)

#define TDIM 256
#define CDIM 64
#define SENT (-1e30f)
#define NPART 512           // stage-1 blocks
#define WS_PART_OFF 16      // float offset of partials in d_ws

typedef __attribute__((ext_vector_type(8))) short bf16x8;
typedef __attribute__((ext_vector_type(4))) float f32x4;

static constexpr float BOA = (float)(0.96963238 / 0.35815147);  // python double then f32 cast
static constexpr float COA = (float)(1.0 / 0.35815147);
static constexpr float AF  = 0.35815147f;
static constexpr float X0F = -0.6931f;

__device__ __forceinline__ int qi8(float x, float s) {
  float r = rintf(x / s);              // IEEE div + round-half-even, matches jnp
  r = fminf(fmaxf(r, -128.f), 127.f);
  return (int)r;
}

__device__ __forceinline__ int pack4q(float4 f, float s) {
  unsigned a = (unsigned)(qi8(f.x, s)) & 255u;
  unsigned b = (unsigned)(qi8(f.y, s)) & 255u;
  unsigned c = (unsigned)(qi8(f.z, s)) & 255u;
  unsigned d = (unsigned)(qi8(f.w, s)) & 255u;
  return (int)(a | (b << 8) | (c << 16) | (d << 24));
}

__device__ __forceinline__ int sx8(int w, int sh) {   // sign-extend byte sh of word w
  return (int)(signed char)((unsigned)w >> sh);
}

__device__ __forceinline__ int dot4(int a, int b, int c) {
#if __has_builtin(__builtin_amdgcn_sdot4)
  return __builtin_amdgcn_sdot4(a, b, c, false);
#else
  c += sx8(a, 0) * sx8(b, 0);
  c += sx8(a, 8) * sx8(b, 8);
  c += sx8(a, 16) * sx8(b, 16);
  c += sx8(a, 24) * sx8(b, 24);
  return c;
#endif
}

__device__ __forceinline__ unsigned short f2bf(float f) {
  // exact for values with <=8 significand bits (our W and V ints)
  return (unsigned short)(__float_as_uint(f) >> 16);
}

// ---- stage 1: per-block max partials (no atomics) ----
__global__ __launch_bounds__(256) void absmax_partial_kernel(
    const float4* __restrict__ q, const float4* __restrict__ k,
    const float4* __restrict__ v, float* __restrict__ ws, int n4) {
  __shared__ float red[3][4];
  int tid = blockIdx.x * 256 + threadIdx.x;
  int stride = gridDim.x * 256;
  float m0 = 0.f, m1 = 0.f, m2 = 0.f;
  for (int i = tid; i < n4; i += stride) {
    float4 a = q[i];
    m0 = fmaxf(m0, fmaxf(fmaxf(fabsf(a.x), fabsf(a.y)), fmaxf(fabsf(a.z), fabsf(a.w))));
    float4 b = k[i];
    m1 = fmaxf(m1, fmaxf(fmaxf(fabsf(b.x), fabsf(b.y)), fmaxf(fabsf(b.z), fabsf(b.w))));
    float4 c = v[i];
    m2 = fmaxf(m2, fmaxf(fmaxf(fabsf(c.x), fabsf(c.y)), fmaxf(fabsf(c.z), fabsf(c.w))));
  }
#pragma unroll
  for (int off = 32; off > 0; off >>= 1) {
    m0 = fmaxf(m0, __shfl_xor(m0, off, 64));
    m1 = fmaxf(m1, __shfl_xor(m1, off, 64));
    m2 = fmaxf(m2, __shfl_xor(m2, off, 64));
  }
  int wave = threadIdx.x >> 6;
  if ((threadIdx.x & 63) == 0) {
    red[0][wave] = m0; red[1][wave] = m1; red[2][wave] = m2;
  }
  __syncthreads();
  if (threadIdx.x == 0) {
    ws[WS_PART_OFF + 0 * NPART + blockIdx.x] = fmaxf(fmaxf(red[0][0], red[0][1]), fmaxf(red[0][2], red[0][3]));
    ws[WS_PART_OFF + 1 * NPART + blockIdx.x] = fmaxf(fmaxf(red[1][0], red[1][1]), fmaxf(red[1][2], red[1][3]));
    ws[WS_PART_OFF + 2 * NPART + blockIdx.x] = fmaxf(fmaxf(red[2][0], red[2][1]), fmaxf(red[2][2], red[2][3]));
  }
}

// ---- stage 2: single block reduces NPART partials per tensor ----
__global__ __launch_bounds__(256) void absmax_final_kernel(float* __restrict__ ws) {
  __shared__ float red[3][4];
  int tid = threadIdx.x;
  int wave = tid >> 6, lane = tid & 63;
#pragma unroll
  for (int j = 0; j < 3; ++j) {
    float v = fmaxf(ws[WS_PART_OFF + j * NPART + tid],
                    ws[WS_PART_OFF + j * NPART + tid + 256]);
#pragma unroll
    for (int off = 32; off > 0; off >>= 1) v = fmaxf(v, __shfl_xor(v, off, 64));
    if (lane == 0) red[j][wave] = v;
  }
  __syncthreads();
  if (tid == 0) {
#pragma unroll
    for (int j = 0; j < 3; ++j)
      ws[j] = fmaxf(fmaxf(red[j][0], red[j][1]), fmaxf(red[j][2], red[j][3]));
  }
}

__global__ __launch_bounds__(256, 2) void head_kernel(
    const float* __restrict__ qg, const float* __restrict__ kg,
    const float* __restrict__ vg, const float* __restrict__ ws,
    float* __restrict__ out, int out_size) {
  __shared__ int qw[TDIM][16];                          // Q rows (broadcast reads, no pad)
  __shared__ int kw[TDIM][17];                          // K rows (+1 word pad)
  __shared__ int vtw[CDIM][66];                         // V^T i8, row stride 264B (8B-aligned)
  __shared__ __align__(16) unsigned short wbuf[2][16][264];  // W bf16, stride 528B, dbuf

  const int tid = threadIdx.x;
  const int b = blockIdx.x;
  const int lane = tid & 63;
  const int wave = tid >> 6;

  // uniform scale pipeline constants (replicate reference f32 op order exactly)
  const float qsf = ws[0] / 127.f;
  const float ksf = ws[1] / 127.f;
  const float vsf = ws[2] / 127.f;
  const float sf = ksf * qsf;                       // wei_sf = k_sf * q_sf
  const float x0i = floorf(X0F / sf);               // x0_int (negative)
  const float bint = floorf(BOA / sf);              // b_int
  const float cint = floorf(COA / (sf * sf));       // c_int
  const float esf = ((AF * sf) * sf) * 0x1p-30f;    // exp_sf = A*sf*sf / 2^30
  const float emax = (cint * 0x1p30f) * esf;        // global max of exp_int*exp_sf
  const float s16 = emax / 32767.f;                 // QuantAct(16) scale
  const float clampv = 30.f * x0i;                  // N_EXP * x0_int

  // ---- load + quantize into LDS ----
  const float4* q4 = (const float4*)(qg + (size_t)b * (TDIM * CDIM));
  const float4* k4 = (const float4*)(kg + (size_t)b * (TDIM * CDIM));
  const float4* v4 = (const float4*)(vg + (size_t)b * (TDIM * CDIM));
  signed char* vtb = (signed char*)vtw;
#pragma unroll
  for (int i = 0; i < 16; ++i) {
    int vidx = i * 256 + tid;        // float4 index 0..4095
    int row = vidx >> 4, cw = vidx & 15;
    float4 f = q4[vidx];
    qw[row][cw] = pack4q(f, qsf);
    f = k4[vidx];
    kw[row][cw] = pack4q(f, ksf);
    f = v4[vidx];
    int c0 = cw << 2;
    vtb[(c0 + 0) * 264 + row] = (signed char)qi8(f.x, vsf);
    vtb[(c0 + 1) * 264 + row] = (signed char)qi8(f.y, vsf);
    vtb[(c0 + 2) * 264 + row] = (signed char)qi8(f.z, vsf);
    vtb[(c0 + 3) * 264 + row] = (signed char)qi8(f.w, vsf);
  }
  __syncthreads();

  const int hi = lane >> 4;
  const int ch_g = (wave << 4) + (lane & 15);     // this wave's output channel
  const int* vcol = vtw[ch_g];

  // ---- cooperative 16-row tiles ----
  for (int T4 = 0; T4 < 16; ++T4) {
    const int buf = T4 & 1;
    // phase 1: QK + int-softmax for 4 rows per wave, write W (bf16) to wbuf
    for (int i = 0; i < 4; ++i) {
      const int r16 = (i << 2) + wave;            // bijective over 0..15 across waves
      const int t = (T4 << 4) + r16;
      const int nch = (t >> 6) + 1;               // active 64-column chunks
      const int* qrow = qw[t];

      float xi[4];
#pragma unroll
      for (int ch = 0; ch < 4; ++ch) {
        int s = (ch << 6) + lane;
        float xv = SENT;
        if (ch < nch && s <= t) {
          const int* krow = kw[s];
          int dot = 0;
#pragma unroll
          for (int w = 0; w < 16; ++w) dot = dot4(qrow[w], krow[w], dot);
          xv = (float)dot * 0.125f;               // exact x_int (multiple of 1/8)
        }
        xi[ch] = xv;
      }

      float m = fmaxf(fmaxf(xi[0], xi[1]), fmaxf(xi[2], xi[3]));
#pragma unroll
      for (int off = 32; off > 0; off >>= 1) m = fmaxf(m, __shfl_xor(m, off, 64));

      float ei[4];
      float lsum = 0.f;
#pragma unroll
      for (int ch = 0; ch < 4; ++ch) {
        float e = 0.f;
        if (xi[ch] > -1e29f) {
          float x = xi[ch] - m;                      // exact (multiples of 1/8)
          x = fmaxf(x, clampv);                      // N_EXP clamp
          float qv = floorf(x / x0i);                // IEEE div
          float r = x - x0i * qv;                    // exact
          float poly = (r + bint) * r + cint;        // no FMA (contract off)
          float ef = floorf(poly * exp2f(30.f - qv));
          ef = fmaxf(ef, 0.f);
          float xf = ef * esf;
          float v16 = rintf(xf / s16);               // QuantAct(16) round
          v16 = fminf(v16, 32767.f);
          e = (v16 * s16) / s16;                     // exp/exp_sf round-trip
        }
        ei[ch] = e;
        lsum += e;
      }
#pragma unroll
      for (int off = 32; off > 0; off >>= 1) lsum += __shfl_xor(lsum, off, 64);

      float factor = floorf(4294967296.f / lsum);
#pragma unroll
      for (int ch = 0; ch < 4; ++ch) {
        float wqf = floorf((ei[ch] * factor) * 0x1p-24f);   // 0..256 integer
        wqf = fminf(fmaxf(wqf, 0.f), 256.f);                // defensive clamp
        wbuf[buf][r16][(ch << 6) + lane] = f2bf(wqf);       // exact bf16
      }
    }
    __syncthreads();

    // phase 2: PV via bf16 MFMA (exact integer arithmetic in f32)
    const int ksteps = (T4 + 2) >> 1;             // ceil(16*(T4+1)/32)
    f32x4 acc = {0.f, 0.f, 0.f, 0.f};
    const unsigned short* wrow = wbuf[buf][lane & 15];
    for (int ks = 0; ks < ksteps; ++ks) {
      bf16x8 a = *(const bf16x8*)(wrow + (ks << 5) + (hi << 3));  // A[row][k0..k7]
      int w0 = vcol[(ks << 3) + (hi << 1)];
      int w1 = vcol[(ks << 3) + (hi << 1) + 1];
      bf16x8 bv;
#pragma unroll
      for (int j = 0; j < 4; ++j) {
        bv[j]     = (short)f2bf((float)sx8(w0, j << 3));
        bv[4 + j] = (short)f2bf((float)sx8(w1, j << 3));
      }
      acc = __builtin_amdgcn_mfma_f32_16x16x32_bf16(a, bv, acc, 0, 0, 0);
    }

    const int rbase = (T4 << 4) + (hi << 2);      // C row = (lane>>4)*4 + reg
#pragma unroll
    for (int j = 0; j < 4; ++j) {
      out[(b * TDIM + rbase + j) * CDIM + ch_g] = (acc[j] * vsf) * 0x1p-16f;
    }
  }

  if (b == 0 && tid == 0) out[out_size - 1] = 0.00390625f;  // wei_sf scalar output
}

extern "C" void kernel_launch(void* const* d_in, const int* in_sizes, int n_in,
                              void* d_out, int out_size, void* d_ws, size_t ws_size,
                              hipStream_t stream) {
  const float* q = (const float*)d_in[0];
  const float* k = (const float*)d_in[1];
  const float* v = (const float*)d_in[2];
  float* out = (float*)d_out;
  float* ws = (float*)d_ws;
  int n = in_sizes[0];               // B*T*C = 8388608
  int nb = n / (TDIM * CDIM);        // 512 batches

  absmax_partial_kernel<<<NPART, 256, 0, stream>>>((const float4*)q, (const float4*)k,
                                                   (const float4*)v, ws, n / 4);
  absmax_final_kernel<<<1, 256, 0, stream>>>(ws);
  head_kernel<<<nb, 256, 0, stream>>>(q, k, v, (const float*)d_ws, out, out_size);
}

// Round 5
// 72.690 us; speedup vs baseline: 7.3916x; 1.9863x over previous
//
#include <hip/hip_runtime.h>

#pragma clang fp contract(off)

#define TDIM 256
#define CDIM 64
#define SENT (-1e30f)
#define NPART 512           // absmax stage-1 blocks
#define WS_PART_OFF 16      // float offset of partials in d_ws

typedef __attribute__((ext_vector_type(8))) short bf16x8;
typedef __attribute__((ext_vector_type(4))) float f32x4;
typedef __attribute__((ext_vector_type(4))) int i32x4;

static constexpr float BOA = (float)(0.96963238 / 0.35815147);
static constexpr float COA = (float)(1.0 / 0.35815147);
static constexpr float AF  = 0.35815147f;
static constexpr float X0F = -0.6931f;

// Markstein exact division: r = RN(1/d) precomputed. Correctly-rounded IEEE
// quotient for normal operands (our ranges are safe) -> bit-identical to '/'.
__device__ __forceinline__ float exdiv(float x, float d, float r) {
  float q0 = x * r;
  float e = __builtin_fmaf(-d, q0, x);
  return __builtin_fmaf(e, r, q0);
}

__device__ __forceinline__ int qi8(float x, float s, float rs) {
  float t = rintf(exdiv(x, s, rs));
  t = fminf(fmaxf(t, -128.f), 127.f);
  return (int)t;
}

__device__ __forceinline__ int pack4q(float4 f, float s, float rs) {
  unsigned a = (unsigned)(qi8(f.x, s, rs)) & 255u;
  unsigned b = (unsigned)(qi8(f.y, s, rs)) & 255u;
  unsigned c = (unsigned)(qi8(f.z, s, rs)) & 255u;
  unsigned d = (unsigned)(qi8(f.w, s, rs)) & 255u;
  return (int)(a | (b << 8) | (c << 16) | (d << 24));
}

__device__ __forceinline__ int sx8(int w, int sh) {
  return (int)(signed char)((unsigned)w >> sh);
}

__device__ __forceinline__ unsigned short f2bf(float f) {
  // exact for our integer-valued inputs (|v| <= 256)
  return (unsigned short)(__float_as_uint(f) >> 16);
}

// ---- absmax stage 1: per-block partials, no atomics ----
__global__ __launch_bounds__(256) void absmax_partial_kernel(
    const float4* __restrict__ q, const float4* __restrict__ k,
    const float4* __restrict__ v, float* __restrict__ ws, int n4) {
  __shared__ float red[3][4];
  int tid = blockIdx.x * 256 + threadIdx.x;
  int stride = gridDim.x * 256;
  float m0 = 0.f, m1 = 0.f, m2 = 0.f;
  for (int i = tid; i < n4; i += stride) {
    float4 a = q[i];
    m0 = fmaxf(m0, fmaxf(fmaxf(fabsf(a.x), fabsf(a.y)), fmaxf(fabsf(a.z), fabsf(a.w))));
    float4 b = k[i];
    m1 = fmaxf(m1, fmaxf(fmaxf(fabsf(b.x), fabsf(b.y)), fmaxf(fabsf(b.z), fabsf(b.w))));
    float4 c = v[i];
    m2 = fmaxf(m2, fmaxf(fmaxf(fabsf(c.x), fabsf(c.y)), fmaxf(fabsf(c.z), fabsf(c.w))));
  }
#pragma unroll
  for (int off = 32; off > 0; off >>= 1) {
    m0 = fmaxf(m0, __shfl_xor(m0, off, 64));
    m1 = fmaxf(m1, __shfl_xor(m1, off, 64));
    m2 = fmaxf(m2, __shfl_xor(m2, off, 64));
  }
  int wave = threadIdx.x >> 6;
  if ((threadIdx.x & 63) == 0) {
    red[0][wave] = m0; red[1][wave] = m1; red[2][wave] = m2;
  }
  __syncthreads();
  if (threadIdx.x == 0) {
    ws[WS_PART_OFF + 0 * NPART + blockIdx.x] = fmaxf(fmaxf(red[0][0], red[0][1]), fmaxf(red[0][2], red[0][3]));
    ws[WS_PART_OFF + 1 * NPART + blockIdx.x] = fmaxf(fmaxf(red[1][0], red[1][1]), fmaxf(red[1][2], red[1][3]));
    ws[WS_PART_OFF + 2 * NPART + blockIdx.x] = fmaxf(fmaxf(red[2][0], red[2][1]), fmaxf(red[2][2], red[2][3]));
  }
}

// ---- absmax stage 2 ----
__global__ __launch_bounds__(256) void absmax_final_kernel(float* __restrict__ ws) {
  __shared__ float red[3][4];
  int tid = threadIdx.x;
  int wave = tid >> 6, lane = tid & 63;
#pragma unroll
  for (int j = 0; j < 3; ++j) {
    float v = fmaxf(ws[WS_PART_OFF + j * NPART + tid],
                    ws[WS_PART_OFF + j * NPART + tid + 256]);
#pragma unroll
    for (int off = 32; off > 0; off >>= 1) v = fmaxf(v, __shfl_xor(v, off, 64));
    if (lane == 0) red[j][wave] = v;
  }
  __syncthreads();
  if (tid == 0) {
#pragma unroll
    for (int j = 0; j < 3; ++j)
      ws[j] = fmaxf(fmaxf(red[j][0], red[j][1]), fmaxf(red[j][2], red[j][3]));
  }
}

__global__ __launch_bounds__(256, 2) void head_kernel(
    const float* __restrict__ qg, const float* __restrict__ kg,
    const float* __restrict__ vg, const float* __restrict__ ws,
    float* __restrict__ out, int out_size) {
  // Q/K int8 in MFMA frag order: word idx = tile*256 + lane*4 + w (16 KB each)
  __shared__ __align__(16) int qf[4096];
  __shared__ __align__(16) int kf[4096];
  // W row-major bf16 [slot][16 rows][264] (stride 528B, 2-way-free both sides);
  // first 16.6 KB doubles as V^T byte staging before the main loop.
  __shared__ __align__(16) unsigned short wrow[4][16][264];

  const int tid = threadIdx.x;
  const int b = blockIdx.x;
  const int lane = tid & 63;
  const int wave = tid >> 6;
  const int hi = lane >> 4;
  const int s15 = lane & 15;

  // uniform scale pipeline constants (replicate reference f32 op order exactly)
  const float qsf = ws[0] / 127.f;
  const float ksf = ws[1] / 127.f;
  const float vsf = ws[2] / 127.f;
  const float sf = ksf * qsf;
  const float x0i = floorf(X0F / sf);
  const float bint = floorf(BOA / sf);
  const float cint = floorf(COA / (sf * sf));
  const float esf = ((AF * sf) * sf) * 0x1p-30f;
  const float emax = (cint * 0x1p30f) * esf;
  const float s16 = emax / 32767.f;
  const float clampv = 30.f * x0i;
  // hoisted IEEE reciprocals for Markstein
  const float rq = 1.f / qsf, rk = 1.f / ksf, rv = 1.f / vsf;
  const float rx0 = 1.f / x0i, rs16 = 1.f / s16;

  // ---- load + quantize ----
  const float4* q4 = (const float4*)(qg + (size_t)b * (TDIM * CDIM));
  const float4* k4 = (const float4*)(kg + (size_t)b * (TDIM * CDIM));
  const float4* v4 = (const float4*)(vg + (size_t)b * (TDIM * CDIM));
  signed char* vst = (signed char*)wrow;   // V^T staging: [c][260B]
#pragma unroll
  for (int i = 0; i < 16; ++i) {
    int vidx = i * 256 + tid;
    int row = vidx >> 4, cw = vidx & 15;
    int fidx = ((row >> 4) << 8) + ((row & 15) << 2) + ((cw >> 2) << 6) + (cw & 3);
    float4 f = q4[vidx];
    qf[fidx] = pack4q(f, qsf, rq);
    f = k4[vidx];
    kf[fidx] = pack4q(f, ksf, rk);
    f = v4[vidx];
    int c0 = cw << 2;
    vst[(c0 + 0) * 260 + row] = (signed char)qi8(f.x, vsf, rv);
    vst[(c0 + 1) * 260 + row] = (signed char)qi8(f.y, vsf, rv);
    vst[(c0 + 2) * 260 + row] = (signed char)qi8(f.z, vsf, rv);
    vst[(c0 + 3) * 260 + row] = (signed char)qi8(f.w, vsf, rv);
  }
  __syncthreads();

  // ---- V -> per-lane bf16 B-frags (channel = wave*16 + s15) ----
  const int myc = (wave << 4) + s15;
  bf16x8 vfrag[8];
#pragma unroll
  for (int ks = 0; ks < 8; ++ks) {
    const signed char* p = vst + myc * 260 + (ks << 5) + (hi << 3);
    int w0, w1;
    __builtin_memcpy(&w0, p, 4);
    __builtin_memcpy(&w1, p + 4, 4);
    bf16x8 bv;
#pragma unroll
    for (int j = 0; j < 4; ++j) {
      bv[j]     = (short)f2bf((float)sx8(w0, j << 3));
      bv[4 + j] = (short)f2bf((float)sx8(w1, j << 3));
    }
    vfrag[ks] = bv;
  }
  __syncthreads();

  // ---- zero W buffer (enables the stale-zero tail argument) ----
  {
    int* wz = (int*)wrow;
#pragma unroll
    for (int i = 0; i < 33; ++i) wz[i * 256 + tid] = 0;
  }
  __syncthreads();

  const i32x4 zero4 = {0, 0, 0, 0};

  // ---- main loop: 4 iterations, wave owns row-tile R = it*4 + wave ----
#pragma unroll 1
  for (int it = 0; it < 4; ++it) {
    const int R = (it << 2) + wave;

    // QK^T via i8 MFMA; xi = x_int (exact), SENT where causally masked
    i32x4 aQ = *(const i32x4*)(qf + (R << 8) + (lane << 2));
    float xi[16][4];
#pragma unroll
    for (int Cc = 0; Cc < 16; ++Cc) {
      if (Cc <= R) {
        i32x4 bK = *(const i32x4*)(kf + (Cc << 8) + (lane << 2));
        i32x4 d = __builtin_amdgcn_mfma_i32_16x16x64_i8(aQ, bK, zero4, 0, 0, 0);
#pragma unroll
        for (int j = 0; j < 4; ++j) {
          bool act = (Cc < R) | (s15 <= ((hi << 2) + j));
          xi[Cc][j] = act ? (float)d[j] * 0.125f : SENT;
        }
      }
    }

    // integer softmax per row (j picks one of this lane-group's 4 rows)
#pragma unroll
    for (int j = 0; j < 4; ++j) {
      float mx = SENT;
#pragma unroll
      for (int Cc = 0; Cc < 16; ++Cc)
        if (Cc <= R) mx = fmaxf(mx, xi[Cc][j]);
      mx = fmaxf(mx, __shfl_xor(mx, 1, 64));
      mx = fmaxf(mx, __shfl_xor(mx, 2, 64));
      mx = fmaxf(mx, __shfl_xor(mx, 4, 64));
      mx = fmaxf(mx, __shfl_xor(mx, 8, 64));

      float lsum = 0.f;
#pragma unroll
      for (int Cc = 0; Cc < 16; ++Cc) {
        if (Cc <= R) {
          float x = xi[Cc][j] - mx;                 // masked: -1e30, caught by clamp
          x = fmaxf(x, clampv);
          float qv = floorf(exdiv(x, x0i, rx0));
          float rr = x - x0i * qv;                  // mul then sub (matches ref)
          float poly = (rr + bint) * rr + cint;     // contract off: no fused fma
          int iq = (int)qv;                         // in [0,30]
          float p2 = __int_as_float((157 - iq) << 23);  // exact 2^(30-q)
          float ef = fmaxf(floorf(poly * p2), 0.f);
          float xf = ef * esf;
          float v16 = fminf(rintf(exdiv(xf, s16, rs16)), 32767.f);
          float e = exdiv(v16 * s16, s16, rs16);
          xi[Cc][j] = e;                            // masked rows -> exactly 0
          lsum += e;
        }
      }
      lsum += __shfl_xor(lsum, 1, 64);
      lsum += __shfl_xor(lsum, 2, 64);
      lsum += __shfl_xor(lsum, 4, 64);
      lsum += __shfl_xor(lsum, 8, 64);

      float factor = floorf(4294967296.f / lsum);   // rare, keep IEEE div
#pragma unroll
      for (int Cc = 0; Cc < 16; ++Cc) {
        if (Cc <= R) {
          float wqf = floorf((xi[Cc][j] * factor) * 0x1p-24f);
          wqf = fminf(fmaxf(wqf, 0.f), 256.f);
          wrow[wave][(hi << 2) + j][(Cc << 4) + s15] = f2bf(wqf);
        }
      }
    }
    __syncthreads();

    // PV: every wave consumes all 4 produced tiles (its 16 channels)
#pragma unroll
    for (int slot = 0; slot < 4; ++slot) {
      const int Rs = (it << 2) + slot;
      const int ksn = (Rs + 2) >> 1;
      f32x4 acc = {0.f, 0.f, 0.f, 0.f};
      const unsigned short* wr = wrow[slot][s15];
#pragma unroll
      for (int ks = 0; ks < 8; ++ks) {
        if (ks < ksn) {
          bf16x8 a = *(const bf16x8*)(wr + (ks << 5) + (hi << 3));
          acc = __builtin_amdgcn_mfma_f32_16x16x32_bf16(a, vfrag[ks], acc, 0, 0, 0);
        }
      }
      const int rbase = (Rs << 4) + (hi << 2);
#pragma unroll
      for (int j = 0; j < 4; ++j)
        out[((b * TDIM) + rbase + j) * CDIM + myc] = (acc[j] * vsf) * 0x1p-16f;
    }
    __syncthreads();
  }

  if (b == 0 && tid == 0) out[out_size - 1] = 0.00390625f;  // wei_sf
}

extern "C" void kernel_launch(void* const* d_in, const int* in_sizes, int n_in,
                              void* d_out, int out_size, void* d_ws, size_t ws_size,
                              hipStream_t stream) {
  const float* q = (const float*)d_in[0];
  const float* k = (const float*)d_in[1];
  const float* v = (const float*)d_in[2];
  float* out = (float*)d_out;
  float* ws = (float*)d_ws;
  int n = in_sizes[0];               // B*T*C = 8388608
  int nb = n / (TDIM * CDIM);        // 512 batches

  absmax_partial_kernel<<<NPART, 256, 0, stream>>>((const float4*)q, (const float4*)k,
                                                   (const float4*)v, ws, n / 4);
  absmax_final_kernel<<<1, 256, 0, stream>>>(ws);
  head_kernel<<<nb, 256, 0, stream>>>(q, k, v, (const float*)d_ws, out, out_size);
}

// Round 6
// 71.556 us; speedup vs baseline: 7.5087x; 1.0158x over previous
//
#include <hip/hip_runtime.h>

#pragma clang fp contract(off)

#define TDIM 256
#define CDIM 64
#define SENT (-1e30f)
#define NPART 512           // absmax stage-1 blocks
#define WS_PART_OFF 16      // float offset of partials in d_ws

typedef __attribute__((ext_vector_type(8))) short bf16x8;
typedef __attribute__((ext_vector_type(4))) float f32x4;
typedef __attribute__((ext_vector_type(4))) int i32x4;

static constexpr float BOA = (float)(0.96963238 / 0.35815147);
static constexpr float COA = (float)(1.0 / 0.35815147);
static constexpr float AF  = 0.35815147f;
static constexpr float X0F = -0.6931f;

// Markstein exact division: r = RN(1/d) precomputed. Correctly-rounded IEEE
// quotient for normal operands (our ranges are safe) -> bit-identical to '/'.
__device__ __forceinline__ float exdiv(float x, float d, float r) {
  float q0 = x * r;
  float e = __builtin_fmaf(-d, q0, x);
  return __builtin_fmaf(e, r, q0);
}

__device__ __forceinline__ int qi8(float x, float s, float rs) {
  float t = rintf(exdiv(x, s, rs));
  t = fminf(fmaxf(t, -128.f), 127.f);
  return (int)t;
}

__device__ __forceinline__ int pack4q(float4 f, float s, float rs) {
  unsigned a = (unsigned)(qi8(f.x, s, rs)) & 255u;
  unsigned b = (unsigned)(qi8(f.y, s, rs)) & 255u;
  unsigned c = (unsigned)(qi8(f.z, s, rs)) & 255u;
  unsigned d = (unsigned)(qi8(f.w, s, rs)) & 255u;
  return (int)(a | (b << 8) | (c << 16) | (d << 24));
}

__device__ __forceinline__ int sx8(int w, int sh) {
  return (int)(signed char)((unsigned)w >> sh);
}

__device__ __forceinline__ unsigned short f2bf(float f) {
  // exact for our integer-valued inputs (|v| <= 256)
  return (unsigned short)(__float_as_uint(f) >> 16);
}

// ---- absmax stage 1: per-block partials, no atomics ----
__global__ __launch_bounds__(256) void absmax_partial_kernel(
    const float4* __restrict__ q, const float4* __restrict__ k,
    const float4* __restrict__ v, float* __restrict__ ws, int n4) {
  __shared__ float red[3][4];
  int tid = blockIdx.x * 256 + threadIdx.x;
  int stride = gridDim.x * 256;
  float m0 = 0.f, m1 = 0.f, m2 = 0.f;
  for (int i = tid; i < n4; i += stride) {
    float4 a = q[i];
    m0 = fmaxf(m0, fmaxf(fmaxf(fabsf(a.x), fabsf(a.y)), fmaxf(fabsf(a.z), fabsf(a.w))));
    float4 b = k[i];
    m1 = fmaxf(m1, fmaxf(fmaxf(fabsf(b.x), fabsf(b.y)), fmaxf(fabsf(b.z), fabsf(b.w))));
    float4 c = v[i];
    m2 = fmaxf(m2, fmaxf(fmaxf(fabsf(c.x), fabsf(c.y)), fmaxf(fabsf(c.z), fabsf(c.w))));
  }
#pragma unroll
  for (int off = 32; off > 0; off >>= 1) {
    m0 = fmaxf(m0, __shfl_xor(m0, off, 64));
    m1 = fmaxf(m1, __shfl_xor(m1, off, 64));
    m2 = fmaxf(m2, __shfl_xor(m2, off, 64));
  }
  int wave = threadIdx.x >> 6;
  if ((threadIdx.x & 63) == 0) {
    red[0][wave] = m0; red[1][wave] = m1; red[2][wave] = m2;
  }
  __syncthreads();
  if (threadIdx.x == 0) {
    ws[WS_PART_OFF + 0 * NPART + blockIdx.x] = fmaxf(fmaxf(red[0][0], red[0][1]), fmaxf(red[0][2], red[0][3]));
    ws[WS_PART_OFF + 1 * NPART + blockIdx.x] = fmaxf(fmaxf(red[1][0], red[1][1]), fmaxf(red[1][2], red[1][3]));
    ws[WS_PART_OFF + 2 * NPART + blockIdx.x] = fmaxf(fmaxf(red[2][0], red[2][1]), fmaxf(red[2][2], red[2][3]));
  }
}

// ---- absmax stage 2 ----
__global__ __launch_bounds__(256) void absmax_final_kernel(float* __restrict__ ws) {
  __shared__ float red[3][4];
  int tid = threadIdx.x;
  int wave = tid >> 6, lane = tid & 63;
#pragma unroll
  for (int j = 0; j < 3; ++j) {
    float v = fmaxf(ws[WS_PART_OFF + j * NPART + tid],
                    ws[WS_PART_OFF + j * NPART + tid + 256]);
#pragma unroll
    for (int off = 32; off > 0; off >>= 1) v = fmaxf(v, __shfl_xor(v, off, 64));
    if (lane == 0) red[j][wave] = v;
  }
  __syncthreads();
  if (tid == 0) {
#pragma unroll
    for (int j = 0; j < 3; ++j)
      ws[j] = fmaxf(fmaxf(red[j][0], red[j][1]), fmaxf(red[j][2], red[j][3]));
  }
}

__global__ __launch_bounds__(256, 3) void head_kernel(
    const float* __restrict__ qg, const float* __restrict__ kg,
    const float* __restrict__ vg, const float* __restrict__ ws,
    float* __restrict__ out, int out_size) {
  // K int8 in MFMA frag order: word idx = tile*256 + lane*4 + w (16 KB)
  __shared__ __align__(16) int kf[4096];
  // W row-major bf16 [slot][16 rows][264] (stride 528B); first 16.6 KB doubles
  // as V^T byte staging before the main loop.  Total LDS = 49 KB -> 3 blk/CU.
  __shared__ __align__(16) unsigned short wrow[4][16][264];

  const int tid = threadIdx.x;
  const int b = blockIdx.x;
  const int lane = tid & 63;
  const int wave = tid >> 6;
  const int hi = lane >> 4;
  const int s15 = lane & 15;

  // uniform scale pipeline constants (replicate reference f32 op order exactly)
  const float qsf = ws[0] / 127.f;
  const float ksf = ws[1] / 127.f;
  const float vsf = ws[2] / 127.f;
  const float sf = ksf * qsf;
  const float x0i = floorf(X0F / sf);
  const float bint = floorf(BOA / sf);
  const float cint = floorf(COA / (sf * sf));
  const float esf = ((AF * sf) * sf) * 0x1p-30f;
  const float emax = (cint * 0x1p30f) * esf;
  const float s16 = emax / 32767.f;
  const float clampv = 30.f * x0i;
  // hoisted IEEE reciprocals for Markstein
  const float rq = 1.f / qsf, rk = 1.f / ksf, rv = 1.f / vsf;
  const float rx0 = 1.f / x0i, rs16 = 1.f / s16;

  // ---- load + quantize K and V (Q is quantized straight into frags later) ----
  const float4* q4 = (const float4*)(qg + (size_t)b * (TDIM * CDIM));
  const float4* k4 = (const float4*)(kg + (size_t)b * (TDIM * CDIM));
  const float4* v4 = (const float4*)(vg + (size_t)b * (TDIM * CDIM));
  signed char* vst = (signed char*)wrow;   // V^T staging: [c][260B]
#pragma unroll
  for (int i = 0; i < 16; ++i) {
    int vidx = i * 256 + tid;
    int row = vidx >> 4, cw = vidx & 15;
    int fidx = ((row >> 4) << 8) + ((row & 15) << 2) + ((cw >> 2) << 6) + (cw & 3);
    float4 f = k4[vidx];
    kf[fidx] = pack4q(f, ksf, rk);
    f = v4[vidx];
    int c0 = cw << 2;
    vst[(c0 + 0) * 260 + row] = (signed char)qi8(f.x, vsf, rv);
    vst[(c0 + 1) * 260 + row] = (signed char)qi8(f.y, vsf, rv);
    vst[(c0 + 2) * 260 + row] = (signed char)qi8(f.z, vsf, rv);
    vst[(c0 + 3) * 260 + row] = (signed char)qi8(f.w, vsf, rv);
  }
  __syncthreads();

  // ---- V -> per-lane bf16 B-frags (channel = wave*16 + s15) ----
  const int myc = (wave << 4) + s15;
  bf16x8 vfrag[8];
#pragma unroll
  for (int ks = 0; ks < 8; ++ks) {
    const signed char* p = vst + myc * 260 + (ks << 5) + (hi << 3);
    int w0, w1;
    __builtin_memcpy(&w0, p, 4);
    __builtin_memcpy(&w1, p + 4, 4);
    bf16x8 bv;
#pragma unroll
    for (int j = 0; j < 4; ++j) {
      bv[j]     = (short)f2bf((float)sx8(w0, j << 3));
      bv[4 + j] = (short)f2bf((float)sx8(w1, j << 3));
    }
    vfrag[ks] = bv;
  }
  __syncthreads();

  // ---- zero W buffer (enables the stale-zero tail argument) ----
  {
    int* wz = (int*)wrow;
#pragma unroll
    for (int i = 0; i < 33; ++i) wz[i * 256 + tid] = 0;
  }
  __syncthreads();

  const i32x4 zero4 = {0, 0, 0, 0};

  // ---- main loop: 4 iterations, wave owns row-tile R = it*4 + wave ----
#pragma unroll 1
  for (int it = 0; it < 4; ++it) {
    const int R = (it << 2) + wave;

    // quantize this wave's Q A-frag directly from global (no LDS round-trip):
    // lane holds A[row = s15][k-bytes hi*16..+15] of tile R
    i32x4 aQ;
    {
      const float4* qrow4 = q4 + ((R << 4) + s15) * 16 + (hi << 2);
      int aw0 = pack4q(qrow4[0], qsf, rq);
      int aw1 = pack4q(qrow4[1], qsf, rq);
      int aw2 = pack4q(qrow4[2], qsf, rq);
      int aw3 = pack4q(qrow4[3], qsf, rq);
      aQ[0] = aw0; aQ[1] = aw1; aQ[2] = aw2; aQ[3] = aw3;
    }

    // QK^T via i8 MFMA; xi = x_int (exact), SENT where causally masked.
    // Sub-diagonal tiles (Cc < R) need no mask; only Cc == R does.
    float xi[16][4];
#pragma unroll
    for (int Cc = 0; Cc < 16; ++Cc) {
      if (Cc < R) {
        i32x4 bK = *(const i32x4*)(kf + (Cc << 8) + (lane << 2));
        i32x4 d = __builtin_amdgcn_mfma_i32_16x16x64_i8(aQ, bK, zero4, 0, 0, 0);
#pragma unroll
        for (int j = 0; j < 4; ++j) xi[Cc][j] = (float)d[j] * 0.125f;
      } else if (Cc == R) {
        i32x4 bK = *(const i32x4*)(kf + (Cc << 8) + (lane << 2));
        i32x4 d = __builtin_amdgcn_mfma_i32_16x16x64_i8(aQ, bK, zero4, 0, 0, 0);
#pragma unroll
        for (int j = 0; j < 4; ++j) {
          bool act = s15 <= ((hi << 2) + j);
          xi[Cc][j] = act ? (float)d[j] * 0.125f : SENT;
        }
      }
    }

    // integer softmax per row (j picks one of this lane-group's 4 rows)
#pragma unroll
    for (int j = 0; j < 4; ++j) {
      float mx = SENT;
#pragma unroll
      for (int Cc = 0; Cc < 16; ++Cc)
        if (Cc <= R) mx = fmaxf(mx, xi[Cc][j]);
      mx = fmaxf(mx, __shfl_xor(mx, 1, 64));
      mx = fmaxf(mx, __shfl_xor(mx, 2, 64));
      mx = fmaxf(mx, __shfl_xor(mx, 4, 64));
      mx = fmaxf(mx, __shfl_xor(mx, 8, 64));

      float lsum = 0.f;
#pragma unroll
      for (int Cc = 0; Cc < 16; ++Cc) {
        if (Cc <= R) {
          float x = xi[Cc][j] - mx;                 // masked: -1e30, caught by clamp
          x = fmaxf(x, clampv);
          float qv = floorf(exdiv(x, x0i, rx0));
          float rr = x - x0i * qv;                  // mul then sub (matches ref)
          float poly = (rr + bint) * rr + cint;     // contract off: no fused fma
          int iq = (int)qv;                         // in [0,30]
          float p2 = __int_as_float((157 - iq) << 23);  // exact 2^(30-q)
          float ef = fmaxf(floorf(poly * p2), 0.f);
          float xf = ef * esf;
          float v16 = fminf(rintf(exdiv(xf, s16, rs16)), 32767.f);
          float e = exdiv(v16 * s16, s16, rs16);
          xi[Cc][j] = e;                            // masked rows -> exactly 0
          lsum += e;
        }
      }
      lsum += __shfl_xor(lsum, 1, 64);
      lsum += __shfl_xor(lsum, 2, 64);
      lsum += __shfl_xor(lsum, 4, 64);
      lsum += __shfl_xor(lsum, 8, 64);

      float factor = floorf(4294967296.f / lsum);   // once per row, keep IEEE div
#pragma unroll
      for (int Cc = 0; Cc < 16; ++Cc) {
        if (Cc <= R) {
          float wqf = floorf((xi[Cc][j] * factor) * 0x1p-24f);
          wqf = fminf(fmaxf(wqf, 0.f), 256.f);
          wrow[wave][(hi << 2) + j][(Cc << 4) + s15] = f2bf(wqf);
        }
      }
    }
    __syncthreads();

    // PV: every wave consumes all 4 produced tiles (its 16 channels)
#pragma unroll
    for (int slot = 0; slot < 4; ++slot) {
      const int Rs = (it << 2) + slot;
      const int ksn = (Rs + 2) >> 1;
      f32x4 acc = {0.f, 0.f, 0.f, 0.f};
      const unsigned short* wr = wrow[slot][s15];
#pragma unroll
      for (int ks = 0; ks < 8; ++ks) {
        if (ks < ksn) {
          bf16x8 a = *(const bf16x8*)(wr + (ks << 5) + (hi << 3));
          acc = __builtin_amdgcn_mfma_f32_16x16x32_bf16(a, vfrag[ks], acc, 0, 0, 0);
        }
      }
      const int rbase = (Rs << 4) + (hi << 2);
#pragma unroll
      for (int j = 0; j < 4; ++j)
        out[((b * TDIM) + rbase + j) * CDIM + myc] = (acc[j] * vsf) * 0x1p-16f;
    }
    __syncthreads();
  }

  if (b == 0 && tid == 0) out[out_size - 1] = 0.00390625f;  // wei_sf
}

extern "C" void kernel_launch(void* const* d_in, const int* in_sizes, int n_in,
                              void* d_out, int out_size, void* d_ws, size_t ws_size,
                              hipStream_t stream) {
  const float* q = (const float*)d_in[0];
  const float* k = (const float*)d_in[1];
  const float* v = (const float*)d_in[2];
  float* out = (float*)d_out;
  float* ws = (float*)d_ws;
  int n = in_sizes[0];               // B*T*C = 8388608
  int nb = n / (TDIM * CDIM);        // 512 batches

  absmax_partial_kernel<<<NPART, 256, 0, stream>>>((const float4*)q, (const float4*)k,
                                                   (const float4*)v, ws, n / 4);
  absmax_final_kernel<<<1, 256, 0, stream>>>(ws);
  head_kernel<<<nb, 256, 0, stream>>>(q, k, v, (const float*)d_ws, out, out_size);
}